// Round 14
// baseline (292.255 us; speedup 1.0000x reference)
//
#include <hip/hip_runtime.h>
#include <hip/hip_fp16.h>
#include <math.h>

#define NN 50000
#define NE 600000
#define IN_DIM 7
#define GE ((NE + 255) / 256)       // 2344 scatter blocks
#define L0_B (NN / 8)               // 6250 layer-0 blocks, 8 nodes each
#define CAP 64                      // bucket capacity (Poisson(12): P(deg>48)~3e-15)
#define CS 16                       // cnt stride in ints: one 64B line per counter

// AB is stored pre-scaled by -2*log2(e) so tanh(a+b) = 2*rcp(1+exp2(a'+b')) - 1
#define NEG2LOG2E -2.8853900817779268f

typedef _Float16 half8 __attribute__((ext_vector_type(8)));
typedef short short8 __attribute__((ext_vector_type(8)));
typedef float f32x4  __attribute__((ext_vector_type(4)));
typedef unsigned int uint;
typedef unsigned short ushort;

#if __has_builtin(__builtin_amdgcn_exp2f)
#define EXP2F(x) __builtin_amdgcn_exp2f(x)
#else
#define EXP2F(x) __expf(0.6931471805599453f * (x))
#endif

// ---------------- merged preamble: scatter | fused-weight prep | head fuse | layer-0 ----------------

__global__ __launch_bounds__(256) void k_pre(
        const float* __restrict__ x,    const int* __restrict__ ei,
        const float* __restrict__ W1_0, const float* __restrict__ b1_0,
        const float* __restrict__ W2_0, const float* __restrict__ b2_0,
        const float* __restrict__ W1s,  const float* __restrict__ b1s,
        const float* __restrict__ W2s,  const float* __restrict__ b2s,
        const float* __restrict__ Wo,
        _Float16* __restrict__ Wt_all, float* __restrict__ dvec_all,
        float* __restrict__ bcat_all, float* __restrict__ Wf,
        float* __restrict__ bfh2, _Float16* __restrict__ AB,
        int* __restrict__ cnt, ushort* __restrict__ bucket) {
    int b = blockIdx.x;
    int t = threadIdx.x;
    if (b < GE) {
        // one-pass CSR: count and place; each counter owns a full cache line
        int e = b * 256 + t;
        if (e < NE) {
            int s = ei[e];
            int d = ei[NE + e];
            int pos = atomicAdd(&cnt[d * CS], 1);
            if (pos < CAP) bucket[d * CAP + pos] = (ushort)s;   // 2B entries
        }
    } else if (b < GE + 385) {
        // fused-weight prep: 2 columns per block
        __shared__ float lds[256];
        int half = t >> 7, tt = t & 127;
        int cidx = (b - GE) * 2 + half;
        if (cidx < 768) {
            int g = cidx >> 8, c = cidx & 255;
            const float* W1g = W1s + (size_t)g * 256 * 128;
            const float* b1g = b1s + (size_t)g * 128;
            const float* W2p = (g == 0) ? W2_0 : W2s + (size_t)(g - 1) * 128 * 128;
            const float* b2p = (g == 0) ? b2_0 : b2s + (size_t)(g - 1) * 128;
            float* wc = &lds[half * 128];
            float v;
            if (c < 128) v = W1g[tt * 128 + c] - W1g[(tt + 128) * 128 + c];
            else         v = W1g[(tt + 128) * 128 + (c - 128)];
            wc[tt] = v;
            __syncthreads();
            float acc = 0.f;
            #pragma unroll 8
            for (int mm = 0; mm < 128; mm++) acc += W2p[tt * 128 + mm] * wc[mm];
            Wt_all[(size_t)g * 32768 + c * 128 + tt] = (_Float16)acc;
            if (tt == 0) {
                float dacc = 0.f;
                for (int mm = 0; mm < 128; mm++) dacc += b2p[mm] * wc[mm];
                dvec_all[g * 256 + c] = dacc;
                bcat_all[g * 256 + c] = (c < 128) ? b1g[c] : 0.f;
            }
        }
    } else if (b == GE + 385) {
        // head fuse: Wf = W2_3 @ Wo; bfh2 = b2_3 @ Wo - colsum(Wf)
        __shared__ float lds[512];
        const float* W2l = W2s + (size_t)2 * 128 * 128;
        const float* b2l = b2s + (size_t)2 * 128;
        if (t < 128) {
            #pragma unroll
            for (int r = 0; r < 3; r++) {
                float acc = 0.f;
                for (int m = 0; m < 128; m++) acc += W2l[t * 128 + m] * Wo[m * 3 + r];
                Wf[t * 3 + r] = acc;
                lds[t * 3 + r] = acc;
            }
        }
        __syncthreads();
        if (t < 3) {
            float acc = 0.f;
            for (int m = 0; m < 128; m++) acc += b2l[m] * Wo[m * 3 + t];
            float wfsum = 0.f;
            for (int m = 0; m < 128; m++) wfsum += lds[m * 3 + t];
            bfh2[t] = acc - wfsum;
        }
    } else {
        // layer-0: 8 nodes/block; thread owns channel c with reg-cached weight col
        int i0 = (b - (GE + 386)) * 8;
        __shared__ float xs[8 * IN_DIM];
        if (t < 8 * IN_DIM) xs[t] = x[i0 * IN_DIM + t];
        int c = t;
        float wcol[IN_DIM];
        float bb;
        if (c < 128) {
            #pragma unroll
            for (int k = 0; k < IN_DIM; k++)
                wcol[k] = W1_0[k * 128 + c] - W1_0[(k + IN_DIM) * 128 + c];
            bb = b1_0[c];
        } else {
            #pragma unroll
            for (int k = 0; k < IN_DIM; k++)
                wcol[k] = W1_0[(k + IN_DIM) * 128 + (c - 128)];
            bb = 0.f;
        }
        __syncthreads();
        #pragma unroll
        for (int r = 0; r < 8; r++) {
            float acc = bb;
            #pragma unroll
            for (int k = 0; k < IN_DIM; k++) acc += xs[r * IN_DIM + k] * wcol[k];
            AB[(size_t)(i0 + r) * 256 + c] = (_Float16)(NEG2LOG2E * acc);
        }
    }
}

// ---------------- agg gather macros (parameterized batch buffer; idx pre-scaled x32) ----------------
// LOAD_B/CONS_B read s0,s1,idxreg,ah,acc,g,qoff,AB4 from enclosing scope; BV is the batch array.

#define LOAD_B(BV, D, SB)                                     \
    {                                                         \
        int jj = (SB) + g;                                    \
        jj = (jj < s1) ? jj : (s1 - 1);                       \
        int sidx = __shfl(idxreg, jj - s0);                   \
        BV[D] = AB4[(size_t)(uint)sidx + qoff];               \
    }
#define CONS_B(BV, D, SB)                                     \
    if ((SB) + g < s1) {                                      \
        uint bh[4] = {BV[D].x, BV[D].y, BV[D].z, BV[D].w};    \
        _Pragma("unroll")                                     \
        for (int k = 0; k < 4; k++) {                         \
            __half2 ua = *reinterpret_cast<__half2*>(&ah[k]); \
            __half2 ub = *reinterpret_cast<__half2*>(&bh[k]); \
            __half2 u2 = __hadd2(ua, ub);                     \
            float2 uf = __half22float2(u2);                   \
            float e0 = EXP2F(uf.x);                           \
            float e1 = EXP2F(uf.y);                           \
            acc[2 * k + 0] += __builtin_amdgcn_rcpf(1.f + e0);\
            acc[2 * k + 1] += __builtin_amdgcn_rcpf(1.f + e1);\
        }                                                     \
    }

// issue the 4-batch prologue for an arbitrary node (shadows s0/s1/idxreg locally)
#define PROLOGUE_FOR(BV, S0X, S1X, IDXX)                      \
    {                                                         \
        int s0 = (S0X), s1 = (S1X);                           \
        int idxreg = (IDXX);                                  \
        if (s0 < s1) {                                        \
            LOAD_B(BV, 0, s0)                                 \
            LOAD_B(BV, 1, s0 + 4)                             \
            LOAD_B(BV, 2, s0 + 8)                             \
            LOAD_B(BV, 3, s0 + 12)                            \
        }                                                     \
    }

// steady-state + tail consumes for the current node (prologue already issued into BV)
#define CONSUME_ALL(BV)                                       \
    if (s0 < s1) {                                            \
        int s = s0;                                           \
        for (; s + 16 < s1; s += 16) {                        \
            CONS_B(BV, 0, s)      LOAD_B(BV, 0, s + 16)       \
            CONS_B(BV, 1, s + 4)  LOAD_B(BV, 1, s + 20)       \
            CONS_B(BV, 2, s + 8)  LOAD_B(BV, 2, s + 24)       \
            CONS_B(BV, 3, s + 12) LOAD_B(BV, 3, s + 28)       \
        }                                                     \
        CONS_B(BV, 0, s)                                      \
        CONS_B(BV, 1, s + 4)                                  \
        CONS_B(BV, 2, s + 8)                                  \
        CONS_B(BV, 3, s + 12)                                 \
    }

// ---------------- fused agg+GEMM (round-13 structure + cross-node batch pipeline) ----------------
// Block = 4 waves x 4 nodes = 16 T-rows in LDS, then MFMA epilogue (4 col-tiles/wave).
// Scalar loads for all 4 nodes hoisted; gather batches double-buffered (bvA/bvB) so
// node j+1's prologue is in flight during node j's consume/reduce/T-write.
// AB double-buffered: reads AB_in, writes AB_out (no aliasing).

__global__ __launch_bounds__(256) void k_agg_gemm(const _Float16* __restrict__ AB_in,
                                                  const int* __restrict__ cnt,
                                                  const ushort* __restrict__ ssrc,
                                                  const _Float16* __restrict__ Wt,
                                                  const float* __restrict__ dvec,
                                                  const float* __restrict__ bcat,
                                                  _Float16* __restrict__ AB_out) {
    __shared__ short Tl[16 * 136];   // 16 T-rows, +8 pad (gemm-proven stride)
    __shared__ float degl[16];
    int t = threadIdx.x;
    int lane = t & 63;
    int wv = t >> 6;
    int q = lane & 15;                   // channel octet
    int g = lane >> 4;                   // edge group 0..3
    const uint4* AB4 = (const uint4*)AB_in;
    int qoff = 16 + q;
    int ibase = blockIdx.x * 16 + wv * 4;

    // ---- hoisted scalar loads: all 12 independent loads in flight together ----
    uint4 avh[4];
    int degh[4];
    int idxh[4];
    int s0h[4], s1h[4];
    #pragma unroll
    for (int j = 0; j < 4; j++) {
        int i = ibase + j;
        avh[j]  = AB4[(size_t)i * 32 + q];
        degh[j] = cnt[i * CS];
        idxh[j] = ((int)ssrc[i * CAP + lane]) << 5;  // scale to uint4 units
    }
    #pragma unroll
    for (int j = 0; j < 4; j++) {
        int d = degh[j];
        if (d > CAP) d = CAP;                        // safety clamp (never hit)
        degh[j] = d;
        s0h[j] = (ibase + j) * CAP;
        s1h[j] = s0h[j] + d;
    }

    // ---- agg phase: 4 nodes per wave, batch-pipelined across nodes ----
    uint4 bvA[4], bvB[4];
    PROLOGUE_FOR(bvA, s0h[0], s1h[0], idxh[0])       // node 0 in flight

    #pragma unroll
    for (int j = 0; j < 4; j++) {
        // issue node j+1's prologue into the OTHER buffer before consuming node j
        if (j < 3) {
            if (j & 1) { PROLOGUE_FOR(bvA, s0h[j + 1], s1h[j + 1], idxh[j + 1]) }
            else       { PROLOGUE_FOR(bvB, s0h[j + 1], s1h[j + 1], idxh[j + 1]) }
        }
        uint ah[4] = {avh[j].x, avh[j].y, avh[j].z, avh[j].w};
        int deg = degh[j];
        int s0 = s0h[j], s1 = s1h[j];
        int idxreg = idxh[j];
        float acc[8];
        #pragma unroll
        for (int k = 0; k < 8; k++) acc[k] = 0.f;
        if (j & 1) { CONSUME_ALL(bvB) } else { CONSUME_ALL(bvA) }

        #pragma unroll
        for (int k = 0; k < 8; k++) {
            acc[k] += __shfl_xor(acc[k], 16);
            acc[k] += __shfl_xor(acc[k], 32);
        }
        if (lane == 0) degl[wv * 4 + j] = (float)deg;
        if (lane < 16) {
            float degf = (float)deg;
            uint4 pv;
            uint* pu = reinterpret_cast<uint*>(&pv);
            #pragma unroll
            for (int k = 0; k < 4; k++) {
                __half2 p = __float22half2_rn(make_float2(
                    2.f * acc[2 * k + 0] - degf, 2.f * acc[2 * k + 1] - degf));
                pu[k] = *reinterpret_cast<uint*>(&p);
            }
            *(uint4*)&Tl[(wv * 4 + j) * 136 + q * 8] = pv;
        }
    }
    __syncthreads();

    // ---- MFMA phase: 16x256 AB tile (round-9 proven layout) ----
    int l15 = lane & 15, quad = lane >> 4;
    int m0 = blockIdx.x * 16;
    const short* Ws = (const short*)Wt;

    half8 a[4];
    #pragma unroll
    for (int ks = 0; ks < 4; ks++) {
        short8 s8 = *(const short8*)&Tl[l15 * 136 + ks * 32 + quad * 8];
        a[ks] = __builtin_bit_cast(half8, s8);
    }

    int c0 = wv * 64;
    #pragma unroll
    for (int ct = 0; ct < 4; ct++) {
        int ccol = c0 + ct * 16 + l15;
        half8 b[4];
        #pragma unroll
        for (int ks = 0; ks < 4; ks++) {
            short8 s8 = *(const short8*)&Ws[ccol * 128 + ks * 32 + quad * 8];
            b[ks] = __builtin_bit_cast(half8, s8);
        }
        float bc = bcat[ccol], dv = dvec[ccol];
        f32x4 acc2 = {0.f, 0.f, 0.f, 0.f};
        #pragma unroll
        for (int ks = 0; ks < 4; ks++)
            acc2 = __builtin_amdgcn_mfma_f32_16x16x32_f16(a[ks], b[ks], acc2, 0, 0, 0);
        #pragma unroll
        for (int r = 0; r < 4; r++) {
            int row = quad * 4 + r;
            float v = acc2[r] + degl[row] * dv + bc;
            AB_out[(size_t)(m0 + row) * 256 + ccol] = (_Float16)(NEG2LOG2E * v);
        }
    }
}

// ---------------- head aggregation: one node/wave (round-5 proven, ushort idx) ----------------

__global__ __launch_bounds__(256) void k_agg_head(const _Float16* __restrict__ AB,
                                                  const int* __restrict__ cnt,
                                                  const ushort* __restrict__ ssrc,
                                                  const float* __restrict__ Wf,
                                                  const float* __restrict__ bfh2,
                                                  const float* __restrict__ bo,
                                                  float* __restrict__ out) {
    int t = threadIdx.x;
    int i = blockIdx.x * 4 + (t >> 6);   // one wave per node
    int lane = t & 63;
    int q = lane & 15;
    int g = lane >> 4;
    const uint4* AB4 = (const uint4*)AB;
    int qoff = 16 + q;

    uint4 av = AB4[(size_t)i * 32 + q];
    int deg = cnt[i * CS];
    int idxreg = ((int)ssrc[i * CAP + lane]) << 5;
    uint ah[4] = {av.x, av.y, av.z, av.w};
    if (deg > CAP) deg = CAP;
    int s0 = i * CAP, s1 = s0 + deg;
    float acc[8];
    #pragma unroll
    for (int k = 0; k < 8; k++) acc[k] = 0.f;
    uint4 bv[4];
    if (s0 < s1) {
        LOAD_B(bv, 0, s0)
        LOAD_B(bv, 1, s0 + 4)
        LOAD_B(bv, 2, s0 + 8)
        LOAD_B(bv, 3, s0 + 12)
    }
    CONSUME_ALL(bv)

    int ch = 8 * q;
    float p0 = 0.f, p1 = 0.f, p2 = 0.f;
    #pragma unroll
    for (int k = 0; k < 8; k++) {
        float v = acc[k];
        p0 += v * Wf[(ch + k) * 3 + 0];
        p1 += v * Wf[(ch + k) * 3 + 1];
        p2 += v * Wf[(ch + k) * 3 + 2];
    }
    #pragma unroll
    for (int o = 32; o > 0; o >>= 1) {
        p0 += __shfl_down(p0, o);
        p1 += __shfl_down(p1, o);
        p2 += __shfl_down(p2, o);
    }
    if (lane == 0) {
        float degf = (float)deg;
        out[i * 3 + 0] = 2.f * p0 + degf * bfh2[0] + bo[0];
        out[i * 3 + 1] = 2.f * p1 + degf * bfh2[1] + bo[1];
        out[i * 3 + 2] = 2.f * p2 + degf * bfh2[2] + bo[2];
    }
}

// ---------------- host ----------------

extern "C" void kernel_launch(void* const* d_in, const int* in_sizes, int n_in,
                              void* d_out, int out_size, void* d_ws, size_t ws_size,
                              hipStream_t stream) {
    const float* x    = (const float*)d_in[0];
    const int*   ei   = (const int*)d_in[1];
    const float* W1_0 = (const float*)d_in[2];
    const float* b1_0 = (const float*)d_in[3];
    const float* W2_0 = (const float*)d_in[4];
    const float* b2_0 = (const float*)d_in[5];
    const float* W1s  = (const float*)d_in[6];
    const float* b1s  = (const float*)d_in[7];
    const float* W2s  = (const float*)d_in[8];
    const float* b2s  = (const float*)d_in[9];
    const float* Wo   = (const float*)d_in[10];
    const float* bo   = (const float*)d_in[11];
    float* out = (float*)d_out;

    char* w = (char*)d_ws;
    _Float16* AB0 = (_Float16*)w;                         w += (size_t)NN * 256 * 2;   // 25.6 MB
    _Float16* AB1 = (_Float16*)w;                         w += (size_t)NN * 256 * 2;   // 25.6 MB
    _Float16* Wt_all = (_Float16*)w;                      w += 3 * 256 * 128 * 2;
    float* dvec = (float*)w;                              w += 3 * 256 * 4;
    float* bcat = (float*)w;                              w += 3 * 256 * 4;
    float* Wf   = (float*)w;                              w += 2048;
    float* bfh2 = (float*)w;                              w += 256;
    int* cnt    = (int*)w;                                w += (size_t)NN * CS * 4;    // 3.2 MB (line-padded)
    ushort* bucket = (ushort*)w;                          w += (size_t)NN * CAP * 2;   // 6.4 MB

    const int B256 = 256;
    int gPre = GE + 386 + L0_B;   // scatter | prep | head | l0
    int gFused = NN / 16;         // 3125 (4 waves x 4 nodes)
    int gHead  = NN / 4;          // 12500 (1 node/wave)

    // ---- preamble: memset + one merged kernel ----
    hipMemsetAsync(cnt, 0, (size_t)NN * CS * 4, stream);
    k_pre<<<gPre, B256, 0, stream>>>(x, ei, W1_0, b1_0, W2_0, b2_0,
                                     W1s, b1s, W2s, b2s, Wo,
                                     Wt_all, dvec, bcat, Wf, bfh2, AB0,
                                     cnt, bucket);

    // ---- fused layer transitions: agg+gemm in one kernel, AB ping-pong ----
    k_agg_gemm<<<gFused, B256, 0, stream>>>(AB0, cnt, bucket, Wt_all,
                                            dvec, bcat, AB1);
    k_agg_gemm<<<gFused, B256, 0, stream>>>(AB1, cnt, bucket, Wt_all + 32768,
                                            dvec + 256, bcat + 256, AB0);
    k_agg_gemm<<<gFused, B256, 0, stream>>>(AB0, cnt, bucket, Wt_all + 65536,
                                            dvec + 512, bcat + 512, AB1);
    k_agg_head<<<gHead, B256, 0, stream>>>(AB1, cnt, bucket, Wf, bfh2, bo, out);
}

// Round 15
// 284.080 us; speedup vs baseline: 1.0288x; 1.0288x over previous
//
#include <hip/hip_runtime.h>
#include <hip/hip_fp16.h>
#include <math.h>

#define NN 50000
#define NE 600000
#define IN_DIM 7
#define GE ((NE + 255) / 256)       // 2344 scatter blocks
#define L0_B (NN / 8)               // 6250 layer-0 blocks, 8 nodes each
#define CAP 64                      // bucket capacity (Poisson(12): P(deg>48)~3e-15)
#define CS 16                       // cnt stride in ints: one 64B line per counter

// AB is stored pre-scaled by -2*log2(e) so tanh(a+b) = 2*rcp(1+exp2(a'+b')) - 1
#define NEG2LOG2E -2.8853900817779268f

typedef _Float16 half8 __attribute__((ext_vector_type(8)));
typedef short short8 __attribute__((ext_vector_type(8)));
typedef float f32x4  __attribute__((ext_vector_type(4)));
typedef unsigned int uint;
typedef unsigned short ushort;

#if __has_builtin(__builtin_amdgcn_exp2f)
#define EXP2F(x) __builtin_amdgcn_exp2f(x)
#else
#define EXP2F(x) __expf(0.6931471805599453f * (x))
#endif

// ---------------- merged preamble: scatter | fused-weight prep | head fuse | layer-0 ----------------

__global__ __launch_bounds__(256) void k_pre(
        const float* __restrict__ x,    const int* __restrict__ ei,
        const float* __restrict__ W1_0, const float* __restrict__ b1_0,
        const float* __restrict__ W2_0, const float* __restrict__ b2_0,
        const float* __restrict__ W1s,  const float* __restrict__ b1s,
        const float* __restrict__ W2s,  const float* __restrict__ b2s,
        const float* __restrict__ Wo,
        _Float16* __restrict__ Wt_all, float* __restrict__ dvec_all,
        float* __restrict__ bcat_all, float* __restrict__ Wf,
        float* __restrict__ bfh2, _Float16* __restrict__ AB,
        int* __restrict__ cnt, ushort* __restrict__ bucket) {
    int b = blockIdx.x;
    int t = threadIdx.x;
    if (b < GE) {
        // one-pass CSR: count and place; each counter owns a full cache line
        int e = b * 256 + t;
        if (e < NE) {
            int s = ei[e];
            int d = ei[NE + e];
            int pos = atomicAdd(&cnt[d * CS], 1);
            if (pos < CAP) bucket[d * CAP + pos] = (ushort)s;   // 2B entries
        }
    } else if (b < GE + 385) {
        // fused-weight prep: 2 columns per block
        __shared__ float lds[256];
        int half = t >> 7, tt = t & 127;
        int cidx = (b - GE) * 2 + half;
        if (cidx < 768) {
            int g = cidx >> 8, c = cidx & 255;
            const float* W1g = W1s + (size_t)g * 256 * 128;
            const float* b1g = b1s + (size_t)g * 128;
            const float* W2p = (g == 0) ? W2_0 : W2s + (size_t)(g - 1) * 128 * 128;
            const float* b2p = (g == 0) ? b2_0 : b2s + (size_t)(g - 1) * 128;
            float* wc = &lds[half * 128];
            float v;
            if (c < 128) v = W1g[tt * 128 + c] - W1g[(tt + 128) * 128 + c];
            else         v = W1g[(tt + 128) * 128 + (c - 128)];
            wc[tt] = v;
            __syncthreads();
            float acc = 0.f;
            #pragma unroll 8
            for (int mm = 0; mm < 128; mm++) acc += W2p[tt * 128 + mm] * wc[mm];
            Wt_all[(size_t)g * 32768 + c * 128 + tt] = (_Float16)acc;
            if (tt == 0) {
                float dacc = 0.f;
                for (int mm = 0; mm < 128; mm++) dacc += b2p[mm] * wc[mm];
                dvec_all[g * 256 + c] = dacc;
                bcat_all[g * 256 + c] = (c < 128) ? b1g[c] : 0.f;
            }
        }
    } else if (b == GE + 385) {
        // head fuse: Wf = W2_3 @ Wo; bfh2 = b2_3 @ Wo - colsum(Wf)
        __shared__ float lds[512];
        const float* W2l = W2s + (size_t)2 * 128 * 128;
        const float* b2l = b2s + (size_t)2 * 128;
        if (t < 128) {
            #pragma unroll
            for (int r = 0; r < 3; r++) {
                float acc = 0.f;
                for (int m = 0; m < 128; m++) acc += W2l[t * 128 + m] * Wo[m * 3 + r];
                Wf[t * 3 + r] = acc;
                lds[t * 3 + r] = acc;
            }
        }
        __syncthreads();
        if (t < 3) {
            float acc = 0.f;
            for (int m = 0; m < 128; m++) acc += b2l[m] * Wo[m * 3 + t];
            float wfsum = 0.f;
            for (int m = 0; m < 128; m++) wfsum += lds[m * 3 + t];
            bfh2[t] = acc - wfsum;
        }
    } else {
        // layer-0: 8 nodes/block; thread owns channel c with reg-cached weight col
        int i0 = (b - (GE + 386)) * 8;
        __shared__ float xs[8 * IN_DIM];
        if (t < 8 * IN_DIM) xs[t] = x[i0 * IN_DIM + t];
        int c = t;
        float wcol[IN_DIM];
        float bb;
        if (c < 128) {
            #pragma unroll
            for (int k = 0; k < IN_DIM; k++)
                wcol[k] = W1_0[k * 128 + c] - W1_0[(k + IN_DIM) * 128 + c];
            bb = b1_0[c];
        } else {
            #pragma unroll
            for (int k = 0; k < IN_DIM; k++)
                wcol[k] = W1_0[(k + IN_DIM) * 128 + (c - 128)];
            bb = 0.f;
        }
        __syncthreads();
        #pragma unroll
        for (int r = 0; r < 8; r++) {
            float acc = bb;
            #pragma unroll
            for (int k = 0; k < IN_DIM; k++) acc += xs[r * IN_DIM + k] * wcol[k];
            AB[(size_t)(i0 + r) * 256 + c] = (_Float16)(NEG2LOG2E * acc);
        }
    }
}

// ---------------- shared agg gather macros (round-5 proven; idx pre-scaled x32 in-register) ----------------

#define LOAD_BATCH(D, SB)                                     \
    {                                                         \
        int jj = (SB) + g;                                    \
        jj = (jj < s1) ? jj : (s1 - 1);                       \
        int sidx = __shfl(idxreg, jj - s0);                   \
        bv[D] = AB4[(size_t)(uint)sidx + qoff];               \
    }
#define CONSUME(D, SB)                                        \
    if ((SB) + g < s1) {                                      \
        uint bh[4] = {bv[D].x, bv[D].y, bv[D].z, bv[D].w};    \
        _Pragma("unroll")                                     \
        for (int k = 0; k < 4; k++) {                         \
            __half2 ua = *reinterpret_cast<__half2*>(&ah[k]); \
            __half2 ub = *reinterpret_cast<__half2*>(&bh[k]); \
            __half2 u2 = __hadd2(ua, ub);                     \
            float2 uf = __half22float2(u2);                   \
            float e0 = EXP2F(uf.x);                           \
            float e1 = EXP2F(uf.y);                           \
            acc[2 * k + 0] += __builtin_amdgcn_rcpf(1.f + e0);\
            acc[2 * k + 1] += __builtin_amdgcn_rcpf(1.f + e1);\
        }                                                     \
    }

#define AGG_LOOP()                                            \
    if (s0 < s1) {                                            \
        LOAD_BATCH(0, s0)                                     \
        LOAD_BATCH(1, s0 + 4)                                 \
        LOAD_BATCH(2, s0 + 8)                                 \
        LOAD_BATCH(3, s0 + 12)                                \
        int s = s0;                                           \
        for (; s + 16 < s1; s += 16) {                        \
            CONSUME(0, s)      LOAD_BATCH(0, s + 16)          \
            CONSUME(1, s + 4)  LOAD_BATCH(1, s + 20)          \
            CONSUME(2, s + 8)  LOAD_BATCH(2, s + 24)          \
            CONSUME(3, s + 12) LOAD_BATCH(3, s + 28)          \
        }                                                     \
        CONSUME(0, s)                                         \
        CONSUME(1, s + 4)                                     \
        CONSUME(2, s + 8)                                     \
        CONSUME(3, s + 12)                                    \
    }

// ---------------- fused agg+GEMM (round-11 proven structure; ushort idx) ----------------
// Block = 4 waves x 4 nodes = 16 T-rows in LDS, then MFMA epilogue (4 col-tiles/wave).
// ALL 12 scalar loads (av/deg/idx x 4 nodes) issue at wave start.
// AB double-buffered: reads AB_in, writes AB_out (no aliasing). Plain stores (L2 write-back).

__global__ __launch_bounds__(256) void k_agg_gemm(const _Float16* __restrict__ AB_in,
                                                  const int* __restrict__ cnt,
                                                  const ushort* __restrict__ ssrc,
                                                  const _Float16* __restrict__ Wt,
                                                  const float* __restrict__ dvec,
                                                  const float* __restrict__ bcat,
                                                  _Float16* __restrict__ AB_out) {
    __shared__ short Tl[16 * 136];   // 16 T-rows, +8 pad (gemm-proven stride)
    __shared__ float degl[16];
    int t = threadIdx.x;
    int lane = t & 63;
    int wv = t >> 6;
    int q = lane & 15;                   // channel octet
    int g = lane >> 4;                   // edge group 0..3
    const uint4* AB4 = (const uint4*)AB_in;
    int qoff = 16 + q;
    int ibase = blockIdx.x * 16 + wv * 4;

    // ---- hoisted scalar loads: all 12 independent loads in flight together ----
    uint4 avh[4];
    int degh[4];
    int idxh[4];
    #pragma unroll
    for (int j = 0; j < 4; j++) {
        int i = ibase + j;
        avh[j]  = AB4[(size_t)i * 32 + q];
        degh[j] = cnt[i * CS];
        idxh[j] = ((int)ssrc[i * CAP + lane]) << 5;  // scale to uint4 units
    }

    // ---- agg phase: 4 nodes per wave, statically unrolled ----
    #pragma unroll
    for (int j = 0; j < 4; j++) {
        int i = ibase + j;
        int idxreg = idxh[j];
        uint ah[4] = {avh[j].x, avh[j].y, avh[j].z, avh[j].w};
        int deg = degh[j];
        if (deg > CAP) deg = CAP;                    // safety clamp (never hit)
        int s0 = i * CAP, s1 = s0 + deg;
        float acc[8];
        #pragma unroll
        for (int k = 0; k < 8; k++) acc[k] = 0.f;
        uint4 bv[4];
        AGG_LOOP()

        #pragma unroll
        for (int k = 0; k < 8; k++) {
            acc[k] += __shfl_xor(acc[k], 16);
            acc[k] += __shfl_xor(acc[k], 32);
        }
        if (lane == 0) degl[wv * 4 + j] = (float)deg;
        if (lane < 16) {
            float degf = (float)deg;
            uint4 pv;
            uint* pu = reinterpret_cast<uint*>(&pv);
            #pragma unroll
            for (int k = 0; k < 4; k++) {
                __half2 p = __float22half2_rn(make_float2(
                    2.f * acc[2 * k + 0] - degf, 2.f * acc[2 * k + 1] - degf));
                pu[k] = *reinterpret_cast<uint*>(&p);
            }
            *(uint4*)&Tl[(wv * 4 + j) * 136 + q * 8] = pv;
        }
    }
    __syncthreads();

    // ---- MFMA phase: 16x256 AB tile (round-9 proven layout) ----
    int l15 = lane & 15, quad = lane >> 4;
    int m0 = blockIdx.x * 16;
    const short* Ws = (const short*)Wt;

    half8 a[4];
    #pragma unroll
    for (int ks = 0; ks < 4; ks++) {
        short8 s8 = *(const short8*)&Tl[l15 * 136 + ks * 32 + quad * 8];
        a[ks] = __builtin_bit_cast(half8, s8);
    }

    int c0 = wv * 64;
    #pragma unroll
    for (int ct = 0; ct < 4; ct++) {
        int ccol = c0 + ct * 16 + l15;
        half8 b[4];
        #pragma unroll
        for (int ks = 0; ks < 4; ks++) {
            short8 s8 = *(const short8*)&Ws[ccol * 128 + ks * 32 + quad * 8];
            b[ks] = __builtin_bit_cast(half8, s8);
        }
        float bc = bcat[ccol], dv = dvec[ccol];
        f32x4 acc2 = {0.f, 0.f, 0.f, 0.f};
        #pragma unroll
        for (int ks = 0; ks < 4; ks++)
            acc2 = __builtin_amdgcn_mfma_f32_16x16x32_f16(a[ks], b[ks], acc2, 0, 0, 0);
        #pragma unroll
        for (int r = 0; r < 4; r++) {
            int row = quad * 4 + r;
            float v = acc2[r] + degl[row] * dv + bc;
            AB_out[(size_t)(m0 + row) * 256 + ccol] = (_Float16)(NEG2LOG2E * v);
        }
    }
}

// ---------------- head aggregation: one node/wave (round-5 proven, ushort idx) ----------------

__global__ __launch_bounds__(256) void k_agg_head(const _Float16* __restrict__ AB,
                                                  const int* __restrict__ cnt,
                                                  const ushort* __restrict__ ssrc,
                                                  const float* __restrict__ Wf,
                                                  const float* __restrict__ bfh2,
                                                  const float* __restrict__ bo,
                                                  float* __restrict__ out) {
    int t = threadIdx.x;
    int i = blockIdx.x * 4 + (t >> 6);   // one wave per node
    int lane = t & 63;
    int q = lane & 15;
    int g = lane >> 4;
    const uint4* AB4 = (const uint4*)AB;
    int qoff = 16 + q;

    uint4 av = AB4[(size_t)i * 32 + q];
    int deg = cnt[i * CS];
    int idxreg = ((int)ssrc[i * CAP + lane]) << 5;
    uint ah[4] = {av.x, av.y, av.z, av.w};
    if (deg > CAP) deg = CAP;
    int s0 = i * CAP, s1 = s0 + deg;
    float acc[8];
    #pragma unroll
    for (int k = 0; k < 8; k++) acc[k] = 0.f;
    uint4 bv[4];
    AGG_LOOP()

    int ch = 8 * q;
    float p0 = 0.f, p1 = 0.f, p2 = 0.f;
    #pragma unroll
    for (int k = 0; k < 8; k++) {
        float v = acc[k];
        p0 += v * Wf[(ch + k) * 3 + 0];
        p1 += v * Wf[(ch + k) * 3 + 1];
        p2 += v * Wf[(ch + k) * 3 + 2];
    }
    #pragma unroll
    for (int o = 32; o > 0; o >>= 1) {
        p0 += __shfl_down(p0, o);
        p1 += __shfl_down(p1, o);
        p2 += __shfl_down(p2, o);
    }
    if (lane == 0) {
        float degf = (float)deg;
        out[i * 3 + 0] = 2.f * p0 + degf * bfh2[0] + bo[0];
        out[i * 3 + 1] = 2.f * p1 + degf * bfh2[1] + bo[1];
        out[i * 3 + 2] = 2.f * p2 + degf * bfh2[2] + bo[2];
    }
}

// ---------------- host ----------------

extern "C" void kernel_launch(void* const* d_in, const int* in_sizes, int n_in,
                              void* d_out, int out_size, void* d_ws, size_t ws_size,
                              hipStream_t stream) {
    const float* x    = (const float*)d_in[0];
    const int*   ei   = (const int*)d_in[1];
    const float* W1_0 = (const float*)d_in[2];
    const float* b1_0 = (const float*)d_in[3];
    const float* W2_0 = (const float*)d_in[4];
    const float* b2_0 = (const float*)d_in[5];
    const float* W1s  = (const float*)d_in[6];
    const float* b1s  = (const float*)d_in[7];
    const float* W2s  = (const float*)d_in[8];
    const float* b2s  = (const float*)d_in[9];
    const float* Wo   = (const float*)d_in[10];
    const float* bo   = (const float*)d_in[11];
    float* out = (float*)d_out;

    char* w = (char*)d_ws;
    _Float16* AB0 = (_Float16*)w;                         w += (size_t)NN * 256 * 2;   // 25.6 MB
    _Float16* AB1 = (_Float16*)w;                         w += (size_t)NN * 256 * 2;   // 25.6 MB
    _Float16* Wt_all = (_Float16*)w;                      w += 3 * 256 * 128 * 2;
    float* dvec = (float*)w;                              w += 3 * 256 * 4;
    float* bcat = (float*)w;                              w += 3 * 256 * 4;
    float* Wf   = (float*)w;                              w += 2048;
    float* bfh2 = (float*)w;                              w += 256;
    int* cnt    = (int*)w;                                w += (size_t)NN * CS * 4;    // 3.2 MB (line-padded)
    ushort* bucket = (ushort*)w;                          w += (size_t)NN * CAP * 2;   // 6.4 MB

    const int B256 = 256;
    int gPre = GE + 386 + L0_B;   // scatter | prep | head | l0
    int gFused = NN / 16;         // 3125 (4 waves x 4 nodes)
    int gHead  = NN / 4;          // 12500 (1 node/wave)

    // ---- preamble: memset + one merged kernel ----
    hipMemsetAsync(cnt, 0, (size_t)NN * CS * 4, stream);
    k_pre<<<gPre, B256, 0, stream>>>(x, ei, W1_0, b1_0, W2_0, b2_0,
                                     W1s, b1s, W2s, b2s, Wo,
                                     Wt_all, dvec, bcat, Wf, bfh2, AB0,
                                     cnt, bucket);

    // ---- fused layer transitions: agg+gemm in one kernel, AB ping-pong ----
    k_agg_gemm<<<gFused, B256, 0, stream>>>(AB0, cnt, bucket, Wt_all,
                                            dvec, bcat, AB1);
    k_agg_gemm<<<gFused, B256, 0, stream>>>(AB1, cnt, bucket, Wt_all + 32768,
                                            dvec + 256, bcat + 256, AB0);
    k_agg_gemm<<<gFused, B256, 0, stream>>>(AB0, cnt, bucket, Wt_all + 65536,
                                            dvec + 512, bcat + 512, AB1);
    k_agg_head<<<gHead, B256, 0, stream>>>(AB1, cnt, bucket, Wf, bfh2, bo, out);
}